// Round 2
// baseline (394.165 us; speedup 1.0000x reference)
//
#include <hip/hip_runtime.h>
#include <hip/hip_bf16.h>

// ---------------- problem constants ----------------
#define N_NODES 4096
#define NE      32768           // raw edges
#define E_TOT   (NE + N_NODES)  // + self loops = 36864
#define IN_FEAT 256
#define HID     64
#define IN_HEAD 64
#define F1      (IN_HEAD * HID)   // 4096
#define OUT_HEAD 5
#define OUT_FEAT 128
#define F2      (OUT_HEAD * OUT_FEAT) // 640
#define NEG_SLOPE 0.2f
#define EPS_A   1e-16f
#define MAX_INIT_ENC 0x007FFFFFu   // encoded(-inf)

typedef __bf16 bf16;
typedef bf16 bf16x8 __attribute__((ext_vector_type(8)));
typedef float f32x4 __attribute__((ext_vector_type(4)));

// monotone float->uint encoding for atomicMax
__device__ inline unsigned enc_f(float f) {
    unsigned u = __float_as_uint(f);
    return (u & 0x80000000u) ? ~u : (u | 0x80000000u);
}
__device__ inline float dec_f(unsigned u) {
    return (u & 0x80000000u) ? __uint_as_float(u & 0x7FFFFFFFu)
                             : __uint_as_float(~u);
}

__device__ inline int edge_dst(const int* __restrict__ ed, int e) {
    return (e < NE) ? ed[e] : (e - NE);
}

// 8-element loads into bf16 fragment: native bf16 or fp32->bf16 convert
__device__ inline bf16x8 ld8(const bf16* p) { return *(const bf16x8*)p; }
__device__ inline bf16x8 ld8(const float* p) {
    f32x4 a = *(const f32x4*)p;
    f32x4 b = *(const f32x4*)(p + 4);
    bf16x8 r;
    r[0] = (bf16)a[0]; r[1] = (bf16)a[1]; r[2] = (bf16)a[2]; r[3] = (bf16)a[3];
    r[4] = (bf16)b[0]; r[5] = (bf16)b[1]; r[6] = (bf16)b[2]; r[7] = (bf16)b[3];
    return r;
}

// ---------------- init ----------------
__global__ void init_kernel(int* counts, unsigned* m1, float* den1,
                            unsigned* m2, float* den2) {
    int i = blockIdx.x * 256 + threadIdx.x;
    if (i < N_NODES) counts[i] = 0;
    if (i < N_NODES * IN_HEAD) { m1[i] = MAX_INIT_ENC; den1[i] = 0.f; }
    if (i < N_NODES * OUT_HEAD) { m2[i] = MAX_INIT_ENC; den2[i] = 0.f; }
}

// ---------------- CSR build ----------------
__global__ void hist_kernel(const int* __restrict__ edst, int* counts) {
    int e = blockIdx.x * 256 + threadIdx.x;
    if (e >= E_TOT) return;
    atomicAdd(&counts[edge_dst(edst, e)], 1);
}

__global__ void scan_kernel(const int* __restrict__ counts,
                            int* __restrict__ row_start, int* __restrict__ cursor) {
    __shared__ int part[256];
    __shared__ int pre[257];
    int t = threadIdx.x;
    int base = t * 16;
    int local[16];
    int s = 0;
#pragma unroll
    for (int i = 0; i < 16; ++i) { local[i] = s; s += counts[base + i]; }
    part[t] = s;
    __syncthreads();
    if (t == 0) {
        int r = 0;
        for (int i = 0; i < 256; ++i) { pre[i] = r; r += part[i]; }
        pre[256] = r;
    }
    __syncthreads();
    int off = pre[t];
#pragma unroll
    for (int i = 0; i < 16; ++i) {
        int v = off + local[i];
        row_start[base + i] = v;
        cursor[base + i] = v;
    }
    if (t == 0) row_start[N_NODES] = pre[256];
}

__global__ void scatter_kernel(const int* __restrict__ edst,
                               int* cursor, int* __restrict__ elist) {
    int e = blockIdx.x * 256 + threadIdx.x;
    if (e >= E_TOT) return;
    int d = edge_dst(edst, e);
    int slot = atomicAdd(&cursor[d], 1);
    elist[slot] = e;
}

// ---------------- bf16 MFMA GEMM: C[M,N] = A[M,K] @ B[K,N] ----------------
// A/B may be fp32 (converted to bf16 during LDS staging) or bf16.
// 64x64 tile / block, 4 waves each 32x32 (2x2 of 16x16x32 mfma).
// Layout (m89/m91-verified): A frag A[m=lane&15][k=quad*8+j]; B frag
// B[n=lane&15][k=quad*8+j]; D: row=quad*4+r, col=lane&15.
template <typename TA, typename TB, typename TC>
__global__ __launch_bounds__(256)
void gemm_kernel(const TA* __restrict__ A, const TB* __restrict__ B,
                 TC* __restrict__ C, int M, int N, int K) {
    __shared__ bf16 As[64][32];
    __shared__ bf16 Bs[32][64];
    const int tid = threadIdx.x;
    const int m0 = blockIdx.y * 64;
    const int n0 = blockIdx.x * 64;
    const int wave = tid >> 6;
    const int lane = tid & 63;
    const int quad = lane >> 4;
    const int lr = lane & 15;
    const int wm = (wave >> 1) * 32;
    const int wn = (wave & 1) * 32;

    const int arow = tid >> 2, acol = (tid & 3) * 8;  // A tile 64x32, 8 elems/thread
    const int brow = tid >> 3, bcol = (tid & 7) * 8;  // B tile 32x64

    f32x4 acc[2][2] = {};

    for (int k0 = 0; k0 < K; k0 += 32) {
        *(bf16x8*)(&As[arow][acol]) = ld8(&A[(size_t)(m0 + arow) * K + k0 + acol]);
        *(bf16x8*)(&Bs[brow][bcol]) = ld8(&B[(size_t)(k0 + brow) * N + n0 + bcol]);
        __syncthreads();

        bf16x8 afrag[2], bfrag[2];
#pragma unroll
        for (int mt = 0; mt < 2; ++mt)
            afrag[mt] = *(const bf16x8*)(&As[wm + mt * 16 + lr][quad * 8]);
#pragma unroll
        for (int nt = 0; nt < 2; ++nt) {
            bf16x8 bv;
#pragma unroll
            for (int j = 0; j < 8; ++j)
                bv[j] = Bs[quad * 8 + j][wn + nt * 16 + lr];
            bfrag[nt] = bv;
        }
#pragma unroll
        for (int mt = 0; mt < 2; ++mt)
#pragma unroll
            for (int nt = 0; nt < 2; ++nt)
                acc[mt][nt] = __builtin_amdgcn_mfma_f32_16x16x32_bf16(
                    afrag[mt], bfrag[nt], acc[mt][nt], 0, 0, 0);
        __syncthreads();
    }

#pragma unroll
    for (int mt = 0; mt < 2; ++mt)
#pragma unroll
        for (int nt = 0; nt < 2; ++nt) {
            int r0 = m0 + wm + mt * 16 + quad * 4;
            int c = n0 + wn + nt * 16 + lr;
#pragma unroll
            for (int r = 0; r < 4; ++r)
                C[(size_t)(r0 + r) * N + c] = (TC)acc[mt][nt][r];
        }
}

// ---------------- layer-1 attention dots ----------------
// a_src1[n][h] = sum_c H1[n][h*64+c]*att_src1[h][c]  (64 heads, 64 hid)
__global__ void att1_kernel(const bf16* __restrict__ H1,
                            const float* __restrict__ as1, const float* __restrict__ ad1,
                            float* __restrict__ a_src, float* __restrict__ a_dst) {
    int n = blockIdx.x;
    int wave = threadIdx.x >> 6, lane = threadIdx.x & 63;
    for (int it = 0; it < 16; ++it) {
        int h = it * 4 + wave;
        float v = (float)H1[(size_t)n * F1 + h * HID + lane];
        float s = v * as1[h * HID + lane];
        float d = v * ad1[h * HID + lane];
#pragma unroll
        for (int off = 32; off > 0; off >>= 1) {
            s += __shfl_down(s, off);
            d += __shfl_down(d, off);
        }
        if (lane == 0) {
            a_src[n * IN_HEAD + h] = s;
            a_dst[n * IN_HEAD + h] = d;
        }
    }
}

// ---------------- layer-2 attention dots ----------------
__global__ void att2_kernel(const float* __restrict__ H2,
                            const float* __restrict__ as2, const float* __restrict__ ad2,
                            float* __restrict__ a_src, float* __restrict__ a_dst) {
    int n = blockIdx.x, h = blockIdx.y, lane = threadIdx.x;
    const float* row = H2 + (size_t)n * F2 + h * OUT_FEAT;
    float v0 = row[lane], v1 = row[lane + 64];
    float s = v0 * as2[h * OUT_FEAT + lane] + v1 * as2[h * OUT_FEAT + lane + 64];
    float d = v0 * ad2[h * OUT_FEAT + lane] + v1 * ad2[h * OUT_FEAT + lane + 64];
#pragma unroll
    for (int off = 32; off > 0; off >>= 1) {
        s += __shfl_down(s, off);
        d += __shfl_down(d, off);
    }
    if (lane == 0) {
        a_src[n * OUT_HEAD + h] = s;
        a_dst[n * OUT_HEAD + h] = d;
    }
}

// ---------------- edge softmax stats (generic over H heads) ----------------
template <int H>
__global__ void edge_max_kernel(const int* __restrict__ es, const int* __restrict__ ed,
                                const float* __restrict__ a_src, const float* __restrict__ a_dst,
                                unsigned* __restrict__ m_enc) {
    int gid = blockIdx.x * 256 + threadIdx.x;
    if (gid >= E_TOT * H) return;
    int e = gid / H, h = gid % H;
    int s = (e < NE) ? es[e] : (e - NE);
    int d = (e < NE) ? ed[e] : (e - NE);
    float l = a_src[s * H + h] + a_dst[d * H + h];
    l = l > 0.f ? l : NEG_SLOPE * l;
    atomicMax(&m_enc[d * H + h], enc_f(l));
}

template <int H>
__global__ void edge_denom_kernel(const int* __restrict__ es, const int* __restrict__ ed,
                                  const float* __restrict__ a_src, const float* __restrict__ a_dst,
                                  const unsigned* __restrict__ m_enc, float* __restrict__ denom) {
    int gid = blockIdx.x * 256 + threadIdx.x;
    if (gid >= E_TOT * H) return;
    int e = gid / H, h = gid % H;
    int s = (e < NE) ? es[e] : (e - NE);
    int d = (e < NE) ? ed[e] : (e - NE);
    float l = a_src[s * H + h] + a_dst[d * H + h];
    l = l > 0.f ? l : NEG_SLOPE * l;
    float ex = expf(l - dec_f(m_enc[d * H + h]));
    atomicAdd(&denom[d * H + h], ex);
}

// ---------------- layer-1 aggregation (block per dst), fused b1+ELU+bf16 ----
__global__ __launch_bounds__(256)
void agg1_kernel(const int* __restrict__ es, const int* __restrict__ row_start,
                 const int* __restrict__ elist,
                 const float* __restrict__ a_src, const float* __restrict__ a_dst,
                 const unsigned* __restrict__ m_enc, const float* __restrict__ denom,
                 const bf16* __restrict__ H1, const float* __restrict__ b1,
                 bf16* __restrict__ h_elu) {
    __shared__ float alpha_s[IN_HEAD];
    int d = blockIdx.x, t = threadIdx.x;
    int beg = row_start[d], end = row_start[d + 1];
    float acc[16];
#pragma unroll
    for (int i = 0; i < 16; ++i) acc[i] = 0.f;

    for (int ei = beg; ei < end; ++ei) {
        int e = elist[ei];
        int s = (e < NE) ? es[e] : d;
        if (t < IN_HEAD) {
            int h = t;
            float l = a_src[s * IN_HEAD + h] + a_dst[d * IN_HEAD + h];
            l = l > 0.f ? l : NEG_SLOPE * l;
            alpha_s[h] = expf(l - dec_f(m_enc[d * IN_HEAD + h])) /
                         (denom[d * IN_HEAD + h] + EPS_A);
        }
        __syncthreads();
        const bf16* Hrow = H1 + (size_t)s * F1;
#pragma unroll
        for (int i = 0; i < 16; ++i) {
            int j = i * 256 + t;
            acc[i] += alpha_s[j >> 6] * (float)Hrow[j];  // j>>6 wave-uniform
        }
        __syncthreads();
    }
#pragma unroll
    for (int i = 0; i < 16; ++i) {
        int j = i * 256 + t;
        float v = acc[i] + b1[j];
        v = v > 0.f ? v : (expf(v) - 1.f);         // ELU
        h_elu[(size_t)d * F1 + j] = (bf16)v;
    }
}

// ---------------- layer-2 aggregation + head-mean + b2 ----------------
__global__ __launch_bounds__(256)
void agg2_kernel(const int* __restrict__ es, const int* __restrict__ row_start,
                 const int* __restrict__ elist,
                 const float* __restrict__ a_src, const float* __restrict__ a_dst,
                 const unsigned* __restrict__ m_enc, const float* __restrict__ denom,
                 const float* __restrict__ H2, const float* __restrict__ b2,
                 float* __restrict__ out_node) {
    __shared__ float alpha_s[OUT_HEAD];
    __shared__ float buf[F2];
    int d = blockIdx.x, t = threadIdx.x;
    int beg = row_start[d], end = row_start[d + 1];
    float acc0 = 0.f, acc1 = 0.f, acc2 = 0.f;

    for (int ei = beg; ei < end; ++ei) {
        int e = elist[ei];
        int s = (e < NE) ? es[e] : d;
        if (t < OUT_HEAD) {
            int h = t;
            float l = a_src[s * OUT_HEAD + h] + a_dst[d * OUT_HEAD + h];
            l = l > 0.f ? l : NEG_SLOPE * l;
            alpha_s[h] = expf(l - dec_f(m_enc[d * OUT_HEAD + h])) /
                         (denom[d * OUT_HEAD + h] + EPS_A);
        }
        __syncthreads();
        const float* Hrow = H2 + (size_t)s * F2;
        acc0 += alpha_s[t >> 7] * Hrow[t];
        acc1 += alpha_s[(t + 256) >> 7] * Hrow[t + 256];
        if (t < 128) acc2 += alpha_s[4] * Hrow[t + 512];
        __syncthreads();
    }
    buf[t] = acc0;
    buf[t + 256] = acc1;
    if (t < 128) buf[t + 512] = acc2;
    __syncthreads();
    if (t < OUT_FEAT) {
        float s = 0.f;
#pragma unroll
        for (int h = 0; h < OUT_HEAD; ++h) s += buf[h * OUT_FEAT + t];
        out_node[(size_t)d * OUT_FEAT + t] = s * (1.f / OUT_HEAD) + b2[t];
    }
}

// ---------------- final node-mean + tanh ----------------
__global__ void final_kernel(const float* __restrict__ out_node, float* __restrict__ out) {
    int c = blockIdx.x, t = threadIdx.x;
    int wave = t >> 6, lane = t & 63;
    float s = 0.f;
    for (int n = t; n < N_NODES; n += 256) s += out_node[(size_t)n * OUT_FEAT + c];
#pragma unroll
    for (int off = 32; off > 0; off >>= 1) s += __shfl_down(s, off);
    __shared__ float ws4[4];
    if (lane == 0) ws4[wave] = s;
    __syncthreads();
    if (t == 0) {
        float tot = ws4[0] + ws4[1] + ws4[2] + ws4[3];
        out[c] = tanhf(tot * (1.f / N_NODES));
    }
}

// ---------------- launch ----------------
extern "C" void kernel_launch(void* const* d_in, const int* in_sizes, int n_in,
                              void* d_out, int out_size, void* d_ws, size_t ws_size,
                              hipStream_t stream) {
    // fp32 inputs (reference dtypes), int32 indices, fp32 output
    const float* x        = (const float*)d_in[0];
    const int*   ei       = (const int*)d_in[1];
    const float* W1       = (const float*)d_in[2];
    const float* att_src1 = (const float*)d_in[3];
    const float* att_dst1 = (const float*)d_in[4];
    const float* b1       = (const float*)d_in[5];
    const float* W2       = (const float*)d_in[6];
    const float* att_src2 = (const float*)d_in[7];
    const float* att_dst2 = (const float*)d_in[8];
    const float* b2       = (const float*)d_in[9];
    float* out = (float*)d_out;

    const int* esrc = ei;
    const int* edst = ei + NE;

    // workspace carve (~82 MB total)
    char* p = (char*)d_ws;
    auto bump = [&](size_t bytes) {
        void* r = (void*)p;
        p += (bytes + 255) & ~(size_t)255;
        return r;
    };
    bf16*     H1       = (bf16*)bump((size_t)N_NODES * F1 * 2);       // 32 MB
    bf16*     h_elu    = (bf16*)bump((size_t)N_NODES * F1 * 2);       // 32 MB
    float*    H2       = (float*)bump((size_t)N_NODES * F2 * 4);      // 10.5 MB
    float*    a_src1   = (float*)bump((size_t)N_NODES * IN_HEAD * 4);
    float*    a_dst1   = (float*)bump((size_t)N_NODES * IN_HEAD * 4);
    unsigned* m_enc1   = (unsigned*)bump((size_t)N_NODES * IN_HEAD * 4);
    float*    denom1   = (float*)bump((size_t)N_NODES * IN_HEAD * 4);
    float*    a_src2   = (float*)bump((size_t)N_NODES * OUT_HEAD * 4);
    float*    a_dst2   = (float*)bump((size_t)N_NODES * OUT_HEAD * 4);
    unsigned* m_enc2   = (unsigned*)bump((size_t)N_NODES * OUT_HEAD * 4);
    float*    denom2   = (float*)bump((size_t)N_NODES * OUT_HEAD * 4);
    int*      counts   = (int*)bump(N_NODES * 4);
    int*      row_start= (int*)bump((N_NODES + 1) * 4);
    int*      cursor   = (int*)bump(N_NODES * 4);
    int*      elist    = (int*)bump(E_TOT * 4);
    float*    out_node = (float*)bump((size_t)N_NODES * OUT_FEAT * 4); // 2 MB

    // 1. init
    init_kernel<<<(N_NODES * IN_HEAD + 255) / 256, 256, 0, stream>>>(
        counts, m_enc1, denom1, m_enc2, denom2);
    // 2. CSR
    hist_kernel<<<(E_TOT + 255) / 256, 256, 0, stream>>>(edst, counts);
    scan_kernel<<<1, 256, 0, stream>>>(counts, row_start, cursor);
    scatter_kernel<<<(E_TOT + 255) / 256, 256, 0, stream>>>(edst, cursor, elist);
    // 3. layer 1
    gemm_kernel<float, float, bf16><<<dim3(F1 / 64, N_NODES / 64), 256, 0, stream>>>(
        x, W1, H1, N_NODES, F1, IN_FEAT);
    att1_kernel<<<N_NODES, 256, 0, stream>>>(H1, att_src1, att_dst1, a_src1, a_dst1);
    edge_max_kernel<IN_HEAD><<<(E_TOT * IN_HEAD + 255) / 256, 256, 0, stream>>>(
        esrc, edst, a_src1, a_dst1, m_enc1);
    edge_denom_kernel<IN_HEAD><<<(E_TOT * IN_HEAD + 255) / 256, 256, 0, stream>>>(
        esrc, edst, a_src1, a_dst1, m_enc1, denom1);
    agg1_kernel<<<N_NODES, 256, 0, stream>>>(
        esrc, row_start, elist, a_src1, a_dst1, m_enc1, denom1, H1, b1, h_elu);
    // 4. layer 2
    gemm_kernel<bf16, float, float><<<dim3(F2 / 64, N_NODES / 64), 256, 0, stream>>>(
        h_elu, W2, H2, N_NODES, F2, F1);
    att2_kernel<<<dim3(N_NODES, OUT_HEAD), 64, 0, stream>>>(
        H2, att_src2, att_dst2, a_src2, a_dst2);
    edge_max_kernel<OUT_HEAD><<<(E_TOT * OUT_HEAD + 255) / 256, 256, 0, stream>>>(
        esrc, edst, a_src2, a_dst2, m_enc2);
    edge_denom_kernel<OUT_HEAD><<<(E_TOT * OUT_HEAD + 255) / 256, 256, 0, stream>>>(
        esrc, edst, a_src2, a_dst2, m_enc2, denom2);
    agg2_kernel<<<N_NODES, 256, 0, stream>>>(
        esrc, row_start, elist, a_src2, a_dst2, m_enc2, denom2, H2, b2, out_node);
    // 5. final
    final_kernel<<<OUT_FEAT, 256, 0, stream>>>(out_node, out);
}

// Round 3
// 342.736 us; speedup vs baseline: 1.1501x; 1.1501x over previous
//
#include <hip/hip_runtime.h>
#include <hip/hip_bf16.h>

// ---------------- problem constants ----------------
#define N_NODES 4096
#define NE      32768           // raw edges
#define E_TOT   (NE + N_NODES)  // + self loops = 36864
#define IN_FEAT 256
#define HID     64
#define IN_HEAD 64
#define F1      4096            // IN_HEAD*HID
#define OUT_HEAD 5
#define OUT_FEAT 128
#define F2      640             // OUT_HEAD*OUT_FEAT
#define NEG_SLOPE 0.2f
#define EPS_A   1e-16f

typedef __bf16 bf16;
typedef bf16 bf16x8 __attribute__((ext_vector_type(8)));
typedef float f32x4 __attribute__((ext_vector_type(4)));

// async global->LDS, 16B per lane; lds base must be wave-uniform (m104/m108)
__device__ inline void async_cp16(bf16* lds, const bf16* g) {
    __builtin_amdgcn_global_load_lds(
        (const __attribute__((address_space(1))) unsigned int*)g,
        (__attribute__((address_space(3))) unsigned int*)lds, 16, 0, 0);
}

// ---------------- CSR build ----------------
__global__ void hist_kernel(const int* __restrict__ edst, int* counts) {
    int e = blockIdx.x * 256 + threadIdx.x;
    if (e >= E_TOT) return;
    int d = (e < NE) ? edst[e] : (e - NE);
    atomicAdd(&counts[d], 1);
}

__global__ void scan_kernel(const int* __restrict__ counts,
                            int* __restrict__ row_start, int* __restrict__ cursor) {
    __shared__ int part[256];
    __shared__ int pre[257];
    int t = threadIdx.x;
    int base = t * 16;
    int local[16];
    int s = 0;
#pragma unroll
    for (int i = 0; i < 16; ++i) { local[i] = s; s += counts[base + i]; }
    part[t] = s;
    __syncthreads();
    if (t == 0) {
        int r = 0;
        for (int i = 0; i < 256; ++i) { pre[i] = r; r += part[i]; }
        pre[256] = r;
    }
    __syncthreads();
    int off = pre[t];
#pragma unroll
    for (int i = 0; i < 16; ++i) {
        int v = off + local[i];
        row_start[base + i] = v;
        cursor[base + i] = v;
    }
    if (t == 0) row_start[N_NODES] = pre[256];
}

__global__ void scatter_kernel(const int* __restrict__ edst,
                               int* cursor, int* __restrict__ elist) {
    int e = blockIdx.x * 256 + threadIdx.x;
    if (e >= E_TOT) return;
    int d = (e < NE) ? edst[e] : (e - NE);
    int slot = atomicAdd(&cursor[d], 1);
    elist[slot] = e;
}

// ---------------- fp32 -> bf16 convert (8 elems/thread) ----------------
__global__ void tobf16_kernel(const float* __restrict__ S, bf16* __restrict__ D, int n8) {
    int i = blockIdx.x * 256 + threadIdx.x;
    if (i >= n8) return;
    f32x4 a = *(const f32x4*)(S + (size_t)i * 8);
    f32x4 b = *(const f32x4*)(S + (size_t)i * 8 + 4);
    bf16x8 r;
    r[0] = (bf16)a[0]; r[1] = (bf16)a[1]; r[2] = (bf16)a[2]; r[3] = (bf16)a[3];
    r[4] = (bf16)b[0]; r[5] = (bf16)b[1]; r[6] = (bf16)b[2]; r[7] = (bf16)b[3];
    *(bf16x8*)(D + (size_t)i * 8) = r;
}

// ---------------- fp32 [R][C] -> bf16 transposed [C][R] ----------------
__global__ void transpose_kernel(const float* __restrict__ S, bf16* __restrict__ D,
                                 int R, int C) {
    __shared__ float tile[32][33];
    int tx = threadIdx.x, ty = threadIdx.y;   // 32 x 8
    int c0 = blockIdx.x * 32, r0 = blockIdx.y * 32;
#pragma unroll
    for (int i = 0; i < 4; ++i)
        tile[ty + i * 8][tx] = S[(size_t)(r0 + ty + i * 8) * C + c0 + tx];
    __syncthreads();
#pragma unroll
    for (int i = 0; i < 4; ++i)
        D[(size_t)(c0 + ty + i * 8) * R + r0 + tx] = (bf16)tile[tx][ty + i * 8];
}

// ---------------- m97-style MFMA GEMM: C[M,N] = A[M,K] @ BT[N,K]^T ----------
// BM=128, BK=32, BN template (128 or 64). 4 waves, each computing 64 x BN/2
// as 4 x (BN/32) frags of 16x16x32. global_load_lds width-16 staging; LDS
// unpadded row-major [rows][32] (required by wave-uniform-base + lane*16).
// Frag layouts (m89/m91-verified): A[m=lane&15][k=quad*8+j] via ds_read_b128;
// D: row=quad*4+r, col=lane&15.
template <int BN, int SPLITK, bool ATOMIC, typename TC>
__global__ __launch_bounds__(256)
void gemm_bt_kernel(const bf16* __restrict__ A, const bf16* __restrict__ BT,
                    TC* __restrict__ C, int M, int N, int K) {
    __shared__ bf16 As[128][32];
    __shared__ bf16 Bs[BN][32];
    const int tid  = threadIdx.x;
    const int wave = tid >> 6, lane = tid & 63;
    const int quad = lane >> 4, lr = lane & 15;
    const int m0 = blockIdx.y * 128, n0 = blockIdx.x * BN;
    const int kchunk = K / SPLITK;
    const int kbeg = blockIdx.z * kchunk;
    const int wm = (wave >> 1) * 64;
    const int wn = (wave & 1) * (BN / 2);
    constexpr int NF = BN / 32;

    const int srow = lane >> 2;        // staging: lane -> row offset 0..15
    const int scol = (lane & 3) * 8;   // staging: lane -> col elem 0/8/16/24

    f32x4 acc[4][NF] = {};

    for (int kk = 0; kk < kchunk; kk += 32) {
        int k0 = kbeg + kk;
        // stage A tile 128x32: each wave stages its 32 rows (2 x 1KB chunks)
#pragma unroll
        for (int c = 0; c < 2; ++c) {
            int r = wave * 32 + c * 16;
            async_cp16(&As[r][0], A + (size_t)(m0 + r + srow) * K + k0 + scol);
        }
        // stage B tile BNx32
#pragma unroll
        for (int c = 0; c < BN / 64; ++c) {
            int r = wave * (BN / 4) + c * 16;
            async_cp16(&Bs[r][0], BT + (size_t)(n0 + r + srow) * K + k0 + scol);
        }
        __syncthreads();   // drains vmcnt (global_load_lds) before LDS reads

        bf16x8 af[4], bfr[NF];
#pragma unroll
        for (int mt = 0; mt < 4; ++mt)
            af[mt] = *(const bf16x8*)(&As[wm + mt * 16 + lr][quad * 8]);
#pragma unroll
        for (int nt = 0; nt < NF; ++nt)
            bfr[nt] = *(const bf16x8*)(&Bs[wn + nt * 16 + lr][quad * 8]);
#pragma unroll
        for (int mt = 0; mt < 4; ++mt)
#pragma unroll
            for (int nt = 0; nt < NF; ++nt)
                acc[mt][nt] = __builtin_amdgcn_mfma_f32_16x16x32_bf16(
                    af[mt], bfr[nt], acc[mt][nt], 0, 0, 0);
        __syncthreads();
    }

#pragma unroll
    for (int mt = 0; mt < 4; ++mt)
#pragma unroll
        for (int nt = 0; nt < NF; ++nt) {
            int row0 = m0 + wm + mt * 16 + quad * 4;
            int col = n0 + wn + nt * 16 + lr;
#pragma unroll
            for (int r = 0; r < 4; ++r) {
                if constexpr (ATOMIC)
                    atomicAdd((float*)&C[(size_t)(row0 + r) * N + col], acc[mt][nt][r]);
                else
                    C[(size_t)(row0 + r) * N + col] = (TC)acc[mt][nt][r];
            }
        }
}

// ---------------- layer-1 attention dots ----------------
__global__ void att1_kernel(const bf16* __restrict__ H1,
                            const float* __restrict__ as1, const float* __restrict__ ad1,
                            float* __restrict__ a_src, float* __restrict__ a_dst) {
    int n = blockIdx.x;
    int wave = threadIdx.x >> 6, lane = threadIdx.x & 63;
    for (int it = 0; it < 16; ++it) {
        int h = it * 4 + wave;
        float v = (float)H1[(size_t)n * F1 + h * HID + lane];
        float s = v * as1[h * HID + lane];
        float d = v * ad1[h * HID + lane];
#pragma unroll
        for (int off = 32; off > 0; off >>= 1) {
            s += __shfl_down(s, off);
            d += __shfl_down(d, off);
        }
        if (lane == 0) {
            a_src[n * IN_HEAD + h] = s;
            a_dst[n * IN_HEAD + h] = d;
        }
    }
}

// ---------------- layer-2 attention dots ----------------
__global__ void att2_kernel(const float* __restrict__ H2,
                            const float* __restrict__ as2, const float* __restrict__ ad2,
                            float* __restrict__ a_src, float* __restrict__ a_dst) {
    int n = blockIdx.x, h = blockIdx.y, lane = threadIdx.x;
    const float* row = H2 + (size_t)n * F2 + h * OUT_FEAT;
    float v0 = row[lane], v1 = row[lane + 64];
    float s = v0 * as2[h * OUT_FEAT + lane] + v1 * as2[h * OUT_FEAT + lane + 64];
    float d = v0 * ad2[h * OUT_FEAT + lane] + v1 * ad2[h * OUT_FEAT + lane + 64];
#pragma unroll
    for (int off = 32; off > 0; off >>= 1) {
        s += __shfl_down(s, off);
        d += __shfl_down(d, off);
    }
    if (lane == 0) {
        a_src[n * OUT_HEAD + h] = s;
        a_dst[n * OUT_HEAD + h] = d;
    }
}

// ------- layer-1 aggregation: in-block softmax stats + gather, fused ELU ----
__global__ __launch_bounds__(256)
void agg1_kernel(const int* __restrict__ es, const int* __restrict__ row_start,
                 const int* __restrict__ elist,
                 const float* __restrict__ a_src, const float* __restrict__ a_dst,
                 const bf16* __restrict__ H1, const float* __restrict__ b1,
                 bf16* __restrict__ h_elu) {
    __shared__ float m_s[IN_HEAD], dinv_s[IN_HEAD];
    __shared__ int src_s[256];
    int d = blockIdx.x, t = threadIdx.x;
    int beg = row_start[d], end = row_start[d + 1], deg = end - beg;

    // per-head online max/denom (t<64), edges read from L2-hot arrays
    if (t < IN_HEAD) {
        float adst = a_dst[d * IN_HEAD + t];
        float m = -1e30f, den = 0.f;
        for (int i = 0; i < deg; ++i) {
            int e = elist[beg + i];
            int s = (e < NE) ? es[e] : d;
            float l = a_src[s * IN_HEAD + t] + adst;
            l = l > 0.f ? l : NEG_SLOPE * l;
            if (l > m) { den = den * __expf(m - l) + 1.f; m = l; }
            else den += __expf(l - m);
        }
        m_s[t] = m;
        dinv_s[t] = 1.f / (den + EPS_A);
    }
    __syncthreads();

    // thread t owns 16 contiguous elems [t*16, t*16+16) -> single head t>>2
    int h = t >> 2;
    float adst = a_dst[d * IN_HEAD + h];
    float m = m_s[h], dinv = dinv_s[h];
    float acc[16];
#pragma unroll
    for (int i = 0; i < 16; ++i) acc[i] = 0.f;

    for (int c0 = 0; c0 < deg; c0 += 256) {
        int cn = min(deg - c0, 256);
        __syncthreads();
        if (t < cn) {
            int e = elist[beg + c0 + t];
            src_s[t] = (e < NE) ? es[e] : d;
        }
        __syncthreads();
        for (int i = 0; i < cn; ++i) {
            int s = src_s[i];
            float l = a_src[s * IN_HEAD + h] + adst;
            l = l > 0.f ? l : NEG_SLOPE * l;
            float alpha = __expf(l - m) * dinv;
            const bf16* Hrow = H1 + (size_t)s * F1 + t * 16;
            bf16x8 v0 = *(const bf16x8*)Hrow;
            bf16x8 v1 = *(const bf16x8*)(Hrow + 8);
#pragma unroll
            for (int j = 0; j < 8; ++j) {
                acc[j]     += alpha * (float)v0[j];
                acc[8 + j] += alpha * (float)v1[j];
            }
        }
    }
#pragma unroll
    for (int j = 0; j < 16; ++j) {
        float v = acc[j] + b1[t * 16 + j];
        acc[j] = v > 0.f ? v : (__expf(v) - 1.f);   // ELU
    }
    bf16x8 o0, o1;
#pragma unroll
    for (int j = 0; j < 8; ++j) { o0[j] = (bf16)acc[j]; o1[j] = (bf16)acc[8 + j]; }
    *(bf16x8*)(h_elu + (size_t)d * F1 + t * 16) = o0;
    *(bf16x8*)(h_elu + (size_t)d * F1 + t * 16 + 8) = o1;
}

// ------- layer-2 aggregation: in-block stats + gather + head-mean + b2 ------
__global__ __launch_bounds__(256)
void agg2_kernel(const int* __restrict__ es, const int* __restrict__ row_start,
                 const int* __restrict__ elist,
                 const float* __restrict__ a_src, const float* __restrict__ a_dst,
                 const float* __restrict__ H2, const float* __restrict__ b2,
                 float* __restrict__ out_node) {
    __shared__ float m_s[OUT_HEAD], dinv_s[OUT_HEAD];
    __shared__ int src_s[256];
    __shared__ float buf[F2];
    int d = blockIdx.x, t = threadIdx.x;
    int beg = row_start[d], end = row_start[d + 1], deg = end - beg;

    if (t < OUT_HEAD) {
        float adst = a_dst[d * OUT_HEAD + t];
        float m = -1e30f, den = 0.f;
        for (int i = 0; i < deg; ++i) {
            int e = elist[beg + i];
            int s = (e < NE) ? es[e] : d;
            float l = a_src[s * OUT_HEAD + t] + adst;
            l = l > 0.f ? l : NEG_SLOPE * l;
            if (l > m) { den = den * __expf(m - l) + 1.f; m = l; }
            else den += __expf(l - m);
        }
        m_s[t] = m;
        dinv_s[t] = 1.f / (den + EPS_A);
    }
    __syncthreads();

    // threads 0..159 own 4 contiguous fp32 at j=t*4; head = t>>5 (128/4=32)
    int h = t >> 5;
    float adst = 0.f, m = 0.f, dinv = 0.f;
    if (t < 160) {
        adst = a_dst[d * OUT_HEAD + h];
        m = m_s[h]; dinv = dinv_s[h];
    }
    float a0 = 0.f, a1 = 0.f, a2 = 0.f, a3 = 0.f;

    for (int c0 = 0; c0 < deg; c0 += 256) {
        int cn = min(deg - c0, 256);
        __syncthreads();
        if (t < cn) {
            int e = elist[beg + c0 + t];
            src_s[t] = (e < NE) ? es[e] : d;
        }
        __syncthreads();
        if (t < 160) {
            for (int i = 0; i < cn; ++i) {
                int s = src_s[i];
                float l = a_src[s * OUT_HEAD + h] + adst;
                l = l > 0.f ? l : NEG_SLOPE * l;
                float alpha = __expf(l - m) * dinv;
                f32x4 v = *(const f32x4*)(H2 + (size_t)s * F2 + t * 4);
                a0 += alpha * v[0]; a1 += alpha * v[1];
                a2 += alpha * v[2]; a3 += alpha * v[3];
            }
        }
    }
    if (t < 160) {
        buf[t * 4 + 0] = a0; buf[t * 4 + 1] = a1;
        buf[t * 4 + 2] = a2; buf[t * 4 + 3] = a3;
    }
    __syncthreads();
    if (t < OUT_FEAT) {
        float s = 0.f;
#pragma unroll
        for (int hh = 0; hh < OUT_HEAD; ++hh) s += buf[hh * OUT_FEAT + t];
        out_node[(size_t)d * OUT_FEAT + t] = s * (1.f / OUT_HEAD) + b2[t];
    }
}

// ---------------- final node-mean + tanh ----------------
__global__ void final_kernel(const float* __restrict__ out_node, float* __restrict__ out) {
    int c = blockIdx.x, t = threadIdx.x;
    int wave = t >> 6, lane = t & 63;
    float s = 0.f;
    for (int n = t; n < N_NODES; n += 256) s += out_node[(size_t)n * OUT_FEAT + c];
#pragma unroll
    for (int off = 32; off > 0; off >>= 1) s += __shfl_down(s, off);
    __shared__ float ws4[4];
    if (lane == 0) ws4[wave] = s;
    __syncthreads();
    if (t == 0) {
        float tot = ws4[0] + ws4[1] + ws4[2] + ws4[3];
        out[c] = tanhf(tot * (1.f / N_NODES));
    }
}

// ---------------- launch ----------------
extern "C" void kernel_launch(void* const* d_in, const int* in_sizes, int n_in,
                              void* d_out, int out_size, void* d_ws, size_t ws_size,
                              hipStream_t stream) {
    const float* x        = (const float*)d_in[0];
    const int*   ei       = (const int*)d_in[1];
    const float* W1       = (const float*)d_in[2];
    const float* att_src1 = (const float*)d_in[3];
    const float* att_dst1 = (const float*)d_in[4];
    const float* b1       = (const float*)d_in[5];
    const float* W2       = (const float*)d_in[6];
    const float* att_src2 = (const float*)d_in[7];
    const float* att_dst2 = (const float*)d_in[8];
    const float* b2       = (const float*)d_in[9];
    float* out = (float*)d_out;

    const int* esrc = ei;
    const int* edst = ei + NE;

    // workspace carve (~88 MB)
    char* p = (char*)d_ws;
    auto bump = [&](size_t bytes) {
        void* r = (void*)p;
        p += (bytes + 255) & ~(size_t)255;
        return r;
    };
    bf16*  H1     = (bf16*)bump((size_t)N_NODES * F1 * 2);        // 32 MB
    bf16*  h_elu  = (bf16*)bump((size_t)N_NODES * F1 * 2);        // 32 MB
    float* H2     = (float*)bump((size_t)N_NODES * F2 * 4);       // 10.5 MB
    bf16*  xb     = (bf16*)bump((size_t)N_NODES * IN_FEAT * 2);   // 2 MB
    bf16*  W1T    = (bf16*)bump((size_t)F1 * IN_FEAT * 2);        // 2 MB
    bf16*  W2T    = (bf16*)bump((size_t)F2 * F1 * 2);             // 5 MB
    float* a_src1 = (float*)bump((size_t)N_NODES * IN_HEAD * 4);
    float* a_dst1 = (float*)bump((size_t)N_NODES * IN_HEAD * 4);
    float* a_src2 = (float*)bump((size_t)N_NODES * OUT_HEAD * 4);
    float* a_dst2 = (float*)bump((size_t)N_NODES * OUT_HEAD * 4);
    int*   counts = (int*)bump(N_NODES * 4);
    int*   row_start = (int*)bump((N_NODES + 1) * 4);
    int*   cursor = (int*)bump(N_NODES * 4);
    int*   elist  = (int*)bump(E_TOT * 4);
    float* out_node = (float*)bump((size_t)N_NODES * OUT_FEAT * 4); // 2 MB

    // zero-init (capture-safe async memsets)
    hipMemsetAsync(counts, 0, N_NODES * 4, stream);
    hipMemsetAsync(H2, 0, (size_t)N_NODES * F2 * 4, stream);

    // CSR
    hist_kernel<<<(E_TOT + 255) / 256, 256, 0, stream>>>(edst, counts);
    scan_kernel<<<1, 256, 0, stream>>>(counts, row_start, cursor);
    scatter_kernel<<<(E_TOT + 255) / 256, 256, 0, stream>>>(edst, cursor, elist);

    // bf16 operand prep
    tobf16_kernel<<<(N_NODES * IN_FEAT / 8 + 255) / 256, 256, 0, stream>>>(
        x, xb, N_NODES * IN_FEAT / 8);
    transpose_kernel<<<dim3(F1 / 32, IN_FEAT / 32), dim3(32, 8), 0, stream>>>(
        W1, W1T, IN_FEAT, F1);
    transpose_kernel<<<dim3(F2 / 32, F1 / 32), dim3(32, 8), 0, stream>>>(
        W2, W2T, F1, F2);

    // layer 1
    gemm_bt_kernel<128, 1, false, bf16><<<dim3(F1 / 128, N_NODES / 128, 1), 256, 0, stream>>>(
        xb, W1T, H1, N_NODES, F1, IN_FEAT);
    att1_kernel<<<N_NODES, 256, 0, stream>>>(H1, a_src1 /*dummy reuse? no*/, a_dst1, a_src1, a_dst1);
    // NOTE: att weights converted on the fly below instead
    // (att1 needs fp32 att vectors; pass the real ones)
    att1_kernel<<<N_NODES, 256, 0, stream>>>(H1, att_src1, att_dst1, a_src1, a_dst1);
    agg1_kernel<<<N_NODES, 256, 0, stream>>>(
        esrc, row_start, elist, a_src1, a_dst1, H1, b1, h_elu);

    // layer 2
    gemm_bt_kernel<64, 2, true, float><<<dim3(F2 / 64, N_NODES / 128, 2), 256, 0, stream>>>(
        h_elu, W2T, H2, N_NODES, F2, F1);
    att2_kernel<<<dim3(N_NODES, OUT_HEAD), 64, 0, stream>>>(
        H2, att_src2, att_dst2, a_src2, a_dst2);
    agg2_kernel<<<N_NODES, 256, 0, stream>>>(
        esrc, row_start, elist, a_src2, a_dst2, H2, b2, out_node);

    // final
    final_kernel<<<OUT_FEAT, 256, 0, stream>>>(out_node, out);
}

// Round 4
// 296.844 us; speedup vs baseline: 1.3279x; 1.1546x over previous
//
#include <hip/hip_runtime.h>
#include <hip/hip_bf16.h>

// ---------------- problem constants ----------------
#define N_NODES 4096
#define NE      32768           // raw edges
#define E_TOT   (NE + N_NODES)  // + self loops = 36864
#define IN_FEAT 256
#define HID     64
#define IN_HEAD 64
#define F1      4096            // IN_HEAD*HID
#define OUT_HEAD 5
#define OUT_FEAT 128
#define F2      640             // OUT_HEAD*OUT_FEAT
#define NEG_SLOPE 0.2f
#define EPS_A   1e-16f

typedef __bf16 bf16;
typedef bf16 bf16x8 __attribute__((ext_vector_type(8)));
typedef float f32x4 __attribute__((ext_vector_type(4)));

// async global->LDS, 16B per lane; lds base must be wave-uniform (m104/m108)
__device__ inline void async_cp16(bf16* lds, const bf16* g) {
    __builtin_amdgcn_global_load_lds(
        (const __attribute__((address_space(1))) unsigned int*)g,
        (__attribute__((address_space(3))) unsigned int*)lds, 16, 0, 0);
}

// ---------------- CSR build ----------------
__global__ void hist_kernel(const int* __restrict__ edst, int* counts) {
    int e = blockIdx.x * 256 + threadIdx.x;
    if (e >= E_TOT) return;
    int d = (e < NE) ? edst[e] : (e - NE);
    atomicAdd(&counts[d], 1);
}

__global__ void scan_kernel(const int* __restrict__ counts,
                            int* __restrict__ row_start, int* __restrict__ cursor) {
    __shared__ int part[256];
    __shared__ int pre[257];
    int t = threadIdx.x;
    int base = t * 16;
    int local[16];
    int s = 0;
#pragma unroll
    for (int i = 0; i < 16; ++i) { local[i] = s; s += counts[base + i]; }
    part[t] = s;
    __syncthreads();
    if (t == 0) {
        int r = 0;
        for (int i = 0; i < 256; ++i) { pre[i] = r; r += part[i]; }
        pre[256] = r;
    }
    __syncthreads();
    int off = pre[t];
#pragma unroll
    for (int i = 0; i < 16; ++i) {
        int v = off + local[i];
        row_start[base + i] = v;
        cursor[base + i] = v;
    }
    if (t == 0) row_start[N_NODES] = pre[256];
}

__global__ void scatter_kernel(const int* __restrict__ edst,
                               int* cursor, int* __restrict__ elist) {
    int e = blockIdx.x * 256 + threadIdx.x;
    if (e >= E_TOT) return;
    int d = (e < NE) ? edst[e] : (e - NE);
    int slot = atomicAdd(&cursor[d], 1);
    elist[slot] = e;
}

// ---------------- fp32 -> bf16 convert (8 elems/thread) ----------------
__global__ void tobf16_kernel(const float* __restrict__ S, bf16* __restrict__ D, int n8) {
    int i = blockIdx.x * 256 + threadIdx.x;
    if (i >= n8) return;
    f32x4 a = *(const f32x4*)(S + (size_t)i * 8);
    f32x4 b = *(const f32x4*)(S + (size_t)i * 8 + 4);
    bf16x8 r;
    r[0] = (bf16)a[0]; r[1] = (bf16)a[1]; r[2] = (bf16)a[2]; r[3] = (bf16)a[3];
    r[4] = (bf16)b[0]; r[5] = (bf16)b[1]; r[6] = (bf16)b[2]; r[7] = (bf16)b[3];
    *(bf16x8*)(D + (size_t)i * 8) = r;
}

// ---------------- fp32 [R][C] -> bf16 transposed [C][R] ----------------
__global__ void transpose_kernel(const float* __restrict__ S, bf16* __restrict__ D,
                                 int R, int C) {
    __shared__ float tile[32][33];
    int tx = threadIdx.x, ty = threadIdx.y;   // 32 x 8
    int c0 = blockIdx.x * 32, r0 = blockIdx.y * 32;
#pragma unroll
    for (int i = 0; i < 4; ++i)
        tile[ty + i * 8][tx] = S[(size_t)(r0 + ty + i * 8) * C + c0 + tx];
    __syncthreads();
#pragma unroll
    for (int i = 0; i < 4; ++i)
        D[(size_t)(c0 + ty + i * 8) * R + r0 + tx] = (bf16)tile[tx][ty + i * 8];
}

// ---------------- MFMA GEMM: C[M,N] = A[M,K] @ BT[N,K]^T ----------------
// BM=128, BK=64, BN in {64,128}. XOR-swizzled LDS: 16B chunk c of row r is
// stored at chunk position c^(r&7) (rows are 128B = 8 chunks). The staging
// lane permutes its GLOBAL column (same 128B line -> coalescing intact,
// global_load_lds lane->LDS mapping unchanged); the frag reader applies the
// same xor. Frag ds_read_b128 bank spread: 2-way (free, m136).
// Frag layouts (m89/m91-verified): A[m=lane&15][k=quad*8+j]; D: row=quad*4+r,
// col=lane&15.
template <int BN, int SPLITK, bool ATOMIC, typename TC>
__global__ __launch_bounds__(256)
void gemm_bt_kernel(const bf16* __restrict__ A, const bf16* __restrict__ BT,
                    TC* __restrict__ C, int M, int N, int K) {
    __shared__ bf16 As[128][64];
    __shared__ bf16 Bs[BN][64];
    const int tid  = threadIdx.x;
    const int wave = tid >> 6, lane = tid & 63;
    const int quad = lane >> 4, lr = lane & 15;
    const int m0 = blockIdx.y * 128, n0 = blockIdx.x * BN;
    const int kchunk = K / SPLITK;
    const int kbeg = blockIdx.z * kchunk;
    const int wm = (wave >> 1) * 64;
    const int wn = (wave & 1) * (BN / 2);
    constexpr int NF = BN / 32;

    const int srow = lane >> 3;                 // 0..7 row offset in 8-row chunk
    const int scol = ((lane & 7) ^ srow) * 8;   // swizzled global column (elems)
    const int xk = lr & 7;                      // frag-read xor key

    f32x4 acc[4][NF] = {};

    for (int kk = 0; kk < kchunk; kk += 64) {
        int k0 = kbeg + kk;
        // stage A 128x64 (16 KB): 4 chunks of 8 rows per wave
#pragma unroll
        for (int c = 0; c < 4; ++c) {
            int r = wave * 32 + c * 8;
            async_cp16(&As[r][0], A + (size_t)(m0 + r + srow) * K + k0 + scol);
        }
        // stage B BNx64: BN/32 chunks per wave
#pragma unroll
        for (int c = 0; c < BN / 32; ++c) {
            int r = wave * (BN / 4) + c * 8;
            async_cp16(&Bs[r][0], BT + (size_t)(n0 + r + srow) * K + k0 + scol);
        }
        __syncthreads();   // drains vmcnt before LDS reads

#pragma unroll
        for (int ks = 0; ks < 2; ++ks) {
            bf16x8 af[4], bfr[NF];
            int ch = ((ks * 4 + quad) ^ xk) * 8;
#pragma unroll
            for (int mt = 0; mt < 4; ++mt)
                af[mt] = *(const bf16x8*)(&As[wm + mt * 16 + lr][ch]);
#pragma unroll
            for (int nt = 0; nt < NF; ++nt)
                bfr[nt] = *(const bf16x8*)(&Bs[wn + nt * 16 + lr][ch]);
#pragma unroll
            for (int mt = 0; mt < 4; ++mt)
#pragma unroll
                for (int nt = 0; nt < NF; ++nt)
                    acc[mt][nt] = __builtin_amdgcn_mfma_f32_16x16x32_bf16(
                        af[mt], bfr[nt], acc[mt][nt], 0, 0, 0);
        }
        __syncthreads();
    }

#pragma unroll
    for (int mt = 0; mt < 4; ++mt)
#pragma unroll
        for (int nt = 0; nt < NF; ++nt) {
            int row0 = m0 + wm + mt * 16 + quad * 4;
            int col = n0 + wn + nt * 16 + lr;
#pragma unroll
            for (int r = 0; r < 4; ++r) {
                if constexpr (ATOMIC)
                    atomicAdd((float*)&C[(size_t)(row0 + r) * N + col], acc[mt][nt][r]);
                else
                    C[(size_t)(row0 + r) * N + col] = (TC)acc[mt][nt][r];
            }
        }
}

// ------- layer-1 attention: fold att vectors into W1 (algebraic identity) ---
// w1s[k][h] = sum_c W1[k][h*64+c] * att_src1[h][c]  (a_src1 = x @ w1s)
__global__ void prep1_kernel(const float* __restrict__ W1,
                             const float* __restrict__ as1, const float* __restrict__ ad1,
                             bf16* __restrict__ w1s, bf16* __restrict__ w1d) {
    int id = blockIdx.x * 256 + threadIdx.x;   // 16384 = 256k x 64h
    int k = id >> 6, h = id & 63;
    const float* wrow = W1 + (size_t)k * F1 + h * HID;
    const float* a1 = as1 + h * HID;
    const float* a2 = ad1 + h * HID;
    float s = 0.f, d = 0.f;
#pragma unroll 8
    for (int c = 0; c < HID; ++c) {
        float w = wrow[c];
        s += w * a1[c];
        d += w * a2[c];
    }
    w1s[id] = (bf16)s;   // layout [k][h] = k*64+h
    w1d[id] = (bf16)d;
}

// a_src1[n][h] = x[n,:] @ w1s[:,h]  — wave per node, lane = head
__global__ __launch_bounds__(256)
void gemv1_kernel(const float* __restrict__ x,
                  const bf16* __restrict__ w1s, const bf16* __restrict__ w1d,
                  float* __restrict__ a_src, float* __restrict__ a_dst) {
    int wave = threadIdx.x >> 6, lane = threadIdx.x & 63;
    int n = blockIdx.x * 4 + wave;
    const float* xr = x + (size_t)n * IN_FEAT;
    float s = 0.f, d = 0.f;
    for (int k0 = 0; k0 < IN_FEAT; k0 += 4) {
        f32x4 xv = *(const f32x4*)(xr + k0);   // wave-uniform -> broadcast
#pragma unroll
        for (int j = 0; j < 4; ++j) {
            float xs = xv[j];
            s += xs * (float)w1s[(k0 + j) * IN_HEAD + lane];
            d += xs * (float)w1d[(k0 + j) * IN_HEAD + lane];
        }
    }
    a_src[n * IN_HEAD + lane] = s;
    a_dst[n * IN_HEAD + lane] = d;
}

// ---------------- layer-2 attention dots ----------------
__global__ void att2_kernel(const float* __restrict__ H2,
                            const float* __restrict__ as2, const float* __restrict__ ad2,
                            float* __restrict__ a_src, float* __restrict__ a_dst) {
    int n = blockIdx.x, h = blockIdx.y, lane = threadIdx.x;
    const float* row = H2 + (size_t)n * F2 + h * OUT_FEAT;
    float v0 = row[lane], v1 = row[lane + 64];
    float s = v0 * as2[h * OUT_FEAT + lane] + v1 * as2[h * OUT_FEAT + lane + 64];
    float d = v0 * ad2[h * OUT_FEAT + lane] + v1 * ad2[h * OUT_FEAT + lane + 64];
#pragma unroll
    for (int off = 32; off > 0; off >>= 1) {
        s += __shfl_down(s, off);
        d += __shfl_down(d, off);
    }
    if (lane == 0) {
        a_src[n * OUT_HEAD + h] = s;
        a_dst[n * OUT_HEAD + h] = d;
    }
}

// ------- layer-1 aggregation: in-block softmax stats + gather, fused ELU ----
__global__ __launch_bounds__(256)
void agg1_kernel(const int* __restrict__ es, const int* __restrict__ row_start,
                 const int* __restrict__ elist,
                 const float* __restrict__ a_src, const float* __restrict__ a_dst,
                 const bf16* __restrict__ H1, const float* __restrict__ b1,
                 bf16* __restrict__ h_elu) {
    __shared__ int src_s[256];
    int d = blockIdx.x, t = threadIdx.x;
    int beg = row_start[d], end = row_start[d + 1], deg = end - beg;

    // online softmax stats: 4 threads per head, shuffle-merged (all threads active)
    int h = t >> 2, sub = t & 3;
    float adst = a_dst[d * IN_HEAD + h];
    float m = -1e30f, den = 0.f;
    for (int i = sub; i < deg; i += 4) {
        int e = elist[beg + i];
        int s = (e < NE) ? es[e] : d;
        float l = a_src[s * IN_HEAD + h] + adst;
        l = l > 0.f ? l : NEG_SLOPE * l;
        if (l > m) { den = den * __expf(m - l) + 1.f; m = l; }
        else den += __expf(l - m);
    }
#pragma unroll
    for (int o = 1; o <= 2; o <<= 1) {
        float mo = __shfl_xor(m, o);
        float dno = __shfl_xor(den, o);
        float mn = fmaxf(m, mo);
        den = den * __expf(m - mn) + dno * __expf(mo - mn);
        m = mn;
    }
    float dinv = 1.f / (den + EPS_A);

    // thread t owns 16 contiguous elems [t*16, t*16+16) -> head t>>2 == h
    float acc[16];
#pragma unroll
    for (int i = 0; i < 16; ++i) acc[i] = 0.f;

    for (int c0 = 0; c0 < deg; c0 += 256) {
        int cn = min(deg - c0, 256);
        __syncthreads();
        if (t < cn) {
            int e = elist[beg + c0 + t];
            src_s[t] = (e < NE) ? es[e] : d;
        }
        __syncthreads();
        for (int i = 0; i < cn; ++i) {
            int s = src_s[i];
            float l = a_src[s * IN_HEAD + h] + adst;
            l = l > 0.f ? l : NEG_SLOPE * l;
            float alpha = __expf(l - m) * dinv;
            const bf16* Hrow = H1 + (size_t)s * F1 + t * 16;
            bf16x8 v0 = *(const bf16x8*)Hrow;
            bf16x8 v1 = *(const bf16x8*)(Hrow + 8);
#pragma unroll
            for (int j = 0; j < 8; ++j) {
                acc[j]     += alpha * (float)v0[j];
                acc[8 + j] += alpha * (float)v1[j];
            }
        }
    }
#pragma unroll
    for (int j = 0; j < 16; ++j) {
        float v = acc[j] + b1[t * 16 + j];
        acc[j] = v > 0.f ? v : (__expf(v) - 1.f);   // ELU
    }
    bf16x8 o0, o1;
#pragma unroll
    for (int j = 0; j < 8; ++j) { o0[j] = (bf16)acc[j]; o1[j] = (bf16)acc[8 + j]; }
    *(bf16x8*)(h_elu + (size_t)d * F1 + t * 16) = o0;
    *(bf16x8*)(h_elu + (size_t)d * F1 + t * 16 + 8) = o1;
}

// ------- layer-2 aggregation: in-block stats + gather + head-mean + b2 ------
__global__ __launch_bounds__(256)
void agg2_kernel(const int* __restrict__ es, const int* __restrict__ row_start,
                 const int* __restrict__ elist,
                 const float* __restrict__ a_src, const float* __restrict__ a_dst,
                 const float* __restrict__ H2, const float* __restrict__ b2,
                 float* __restrict__ out_node) {
    __shared__ float m_s[OUT_HEAD], dinv_s[OUT_HEAD];
    __shared__ int src_s[256];
    __shared__ float buf[F2];
    int d = blockIdx.x, t = threadIdx.x;
    int beg = row_start[d], end = row_start[d + 1], deg = end - beg;

    // stats: 8 threads per head (t<40, wave 0), shuffle-merged
    if (t < 40) {
        int hh = t >> 3, sub = t & 7;
        float adst = a_dst[d * OUT_HEAD + hh];
        float m = -1e30f, den = 0.f;
        for (int i = sub; i < deg; i += 8) {
            int e = elist[beg + i];
            int s = (e < NE) ? es[e] : d;
            float l = a_src[s * OUT_HEAD + hh] + adst;
            l = l > 0.f ? l : NEG_SLOPE * l;
            if (l > m) { den = den * __expf(m - l) + 1.f; m = l; }
            else den += __expf(l - m);
        }
#pragma unroll
        for (int o = 1; o <= 4; o <<= 1) {
            float mo = __shfl_xor(m, o);
            float dno = __shfl_xor(den, o);
            float mn = fmaxf(m, mo);
            den = den * __expf(m - mn) + dno * __expf(mo - mn);
            m = mn;
        }
        if (sub == 0) { m_s[hh] = m; dinv_s[hh] = 1.f / (den + EPS_A); }
    }
    __syncthreads();

    // threads 0..159 own 4 contiguous fp32 at j=t*4; head = t>>5
    int h = t >> 5;
    float adst = 0.f, m = 0.f, dinv = 0.f;
    if (t < 160) {
        adst = a_dst[d * OUT_HEAD + h];
        m = m_s[h]; dinv = dinv_s[h];
    }
    float a0 = 0.f, a1 = 0.f, a2 = 0.f, a3 = 0.f;

    for (int c0 = 0; c0 < deg; c0 += 256) {
        int cn = min(deg - c0, 256);
        __syncthreads();
        if (t < cn) {
            int e = elist[beg + c0 + t];
            src_s[t] = (e < NE) ? es[e] : d;
        }
        __syncthreads();
        if (t < 160) {
            for (int i = 0; i < cn; ++i) {
                int s = src_s[i];
                float l = a_src[s * OUT_HEAD + h] + adst;
                l = l > 0.f ? l : NEG_SLOPE * l;
                float alpha = __expf(l - m) * dinv;
                f32x4 v = *(const f32x4*)(H2 + (size_t)s * F2 + t * 4);
                a0 += alpha * v[0]; a1 += alpha * v[1];
                a2 += alpha * v[2]; a3 += alpha * v[3];
            }
        }
    }
    if (t < 160) {
        buf[t * 4 + 0] = a0; buf[t * 4 + 1] = a1;
        buf[t * 4 + 2] = a2; buf[t * 4 + 3] = a3;
    }
    __syncthreads();
    if (t < OUT_FEAT) {
        float s = 0.f;
#pragma unroll
        for (int hh = 0; hh < OUT_HEAD; ++hh) s += buf[hh * OUT_FEAT + t];
        out_node[(size_t)d * OUT_FEAT + t] = s * (1.f / OUT_HEAD) + b2[t];
    }
}

// ---------------- final node-mean + tanh ----------------
__global__ void final_kernel(const float* __restrict__ out_node, float* __restrict__ out) {
    int c = blockIdx.x, t = threadIdx.x;
    int wave = t >> 6, lane = t & 63;
    float s = 0.f;
    for (int n = t; n < N_NODES; n += 256) s += out_node[(size_t)n * OUT_FEAT + c];
#pragma unroll
    for (int off = 32; off > 0; off >>= 1) s += __shfl_down(s, off);
    __shared__ float ws4[4];
    if (lane == 0) ws4[wave] = s;
    __syncthreads();
    if (t == 0) {
        float tot = ws4[0] + ws4[1] + ws4[2] + ws4[3];
        out[c] = tanhf(tot * (1.f / N_NODES));
    }
}

// ---------------- launch ----------------
extern "C" void kernel_launch(void* const* d_in, const int* in_sizes, int n_in,
                              void* d_out, int out_size, void* d_ws, size_t ws_size,
                              hipStream_t stream) {
    const float* x        = (const float*)d_in[0];
    const int*   ei       = (const int*)d_in[1];
    const float* W1       = (const float*)d_in[2];
    const float* att_src1 = (const float*)d_in[3];
    const float* att_dst1 = (const float*)d_in[4];
    const float* b1       = (const float*)d_in[5];
    const float* W2       = (const float*)d_in[6];
    const float* att_src2 = (const float*)d_in[7];
    const float* att_dst2 = (const float*)d_in[8];
    const float* b2       = (const float*)d_in[9];
    float* out = (float*)d_out;

    const int* esrc = ei;
    const int* edst = ei + NE;

    // workspace carve (~88 MB)
    char* p = (char*)d_ws;
    auto bump = [&](size_t bytes) {
        void* r = (void*)p;
        p += (bytes + 255) & ~(size_t)255;
        return r;
    };
    bf16*  H1     = (bf16*)bump((size_t)N_NODES * F1 * 2);        // 32 MB
    bf16*  h_elu  = (bf16*)bump((size_t)N_NODES * F1 * 2);        // 32 MB
    float* H2     = (float*)bump((size_t)N_NODES * F2 * 4);       // 10.5 MB
    bf16*  xb     = (bf16*)bump((size_t)N_NODES * IN_FEAT * 2);   // 2 MB
    bf16*  W1T    = (bf16*)bump((size_t)F1 * IN_FEAT * 2);        // 2 MB
    bf16*  W2T    = (bf16*)bump((size_t)F2 * F1 * 2);             // 5 MB
    bf16*  w1s    = (bf16*)bump((size_t)IN_FEAT * IN_HEAD * 2);
    bf16*  w1d    = (bf16*)bump((size_t)IN_FEAT * IN_HEAD * 2);
    float* a_src1 = (float*)bump((size_t)N_NODES * IN_HEAD * 4);
    float* a_dst1 = (float*)bump((size_t)N_NODES * IN_HEAD * 4);
    float* a_src2 = (float*)bump((size_t)N_NODES * OUT_HEAD * 4);
    float* a_dst2 = (float*)bump((size_t)N_NODES * OUT_HEAD * 4);
    int*   counts = (int*)bump(N_NODES * 4);
    int*   row_start = (int*)bump((N_NODES + 1) * 4);
    int*   cursor = (int*)bump(N_NODES * 4);
    int*   elist  = (int*)bump(E_TOT * 4);
    float* out_node = (float*)bump((size_t)N_NODES * OUT_FEAT * 4); // 2 MB

    // zero-init (capture-safe async memsets)
    hipMemsetAsync(counts, 0, N_NODES * 4, stream);
    hipMemsetAsync(H2, 0, (size_t)N_NODES * F2 * 4, stream);

    // CSR
    hist_kernel<<<(E_TOT + 255) / 256, 256, 0, stream>>>(edst, counts);
    scan_kernel<<<1, 256, 0, stream>>>(counts, row_start, cursor);
    scatter_kernel<<<(E_TOT + 255) / 256, 256, 0, stream>>>(edst, cursor, elist);

    // operand prep
    tobf16_kernel<<<(N_NODES * IN_FEAT / 8 + 255) / 256, 256, 0, stream>>>(
        x, xb, N_NODES * IN_FEAT / 8);
    transpose_kernel<<<dim3(F1 / 32, IN_FEAT / 32), dim3(32, 8), 0, stream>>>(
        W1, W1T, IN_FEAT, F1);
    transpose_kernel<<<dim3(F2 / 32, F1 / 32), dim3(32, 8), 0, stream>>>(
        W2, W2T, F1, F2);
    prep1_kernel<<<IN_FEAT * IN_HEAD / 256, 256, 0, stream>>>(
        W1, att_src1, att_dst1, w1s, w1d);

    // layer 1
    gemm_bt_kernel<128, 1, false, bf16><<<dim3(F1 / 128, N_NODES / 128, 1), 256, 0, stream>>>(
        xb, W1T, H1, N_NODES, F1, IN_FEAT);
    gemv1_kernel<<<N_NODES / 4, 256, 0, stream>>>(x, w1s, w1d, a_src1, a_dst1);
    agg1_kernel<<<N_NODES, 256, 0, stream>>>(
        esrc, row_start, elist, a_src1, a_dst1, H1, b1, h_elu);

    // layer 2
    gemm_bt_kernel<64, 4, true, float><<<dim3(F2 / 64, N_NODES / 128, 4), 256, 0, stream>>>(
        h_elu, W2T, H2, N_NODES, F2, F1);
    att2_kernel<<<dim3(N_NODES, OUT_HEAD), 64, 0, stream>>>(
        H2, att_src2, att_dst2, a_src2, a_dst2);
    agg2_kernel<<<N_NODES, 256, 0, stream>>>(
        esrc, row_start, elist, a_src2, a_dst2, H2, b2, out_node);

    // final
    final_kernel<<<OUT_FEAT, 256, 0, stream>>>(out_node, out);
}